// Round 5
// baseline (1332.935 us; speedup 1.0000x reference)
//
#include <hip/hip_runtime.h>

#define BATCH 256
#define TT 4096
#define NS 32
#define NI 8
#define NO 8
#define LCH 64
#define NCHUNKS 64  // TT / LCH

// ws layout (floats)
#define WS_M  0
#define WS_N0 1024
#define WS_N1 1280
#define WS_ML 1536
#define WS_V  2560
#define WS_S  (2560 + BATCH * NCHUNKS * NS)
#define WS_F  (WS_S + BATCH * NCHUNKS * NS)  // [LCH+1][NS][NI]

__device__ __forceinline__ float dot4(float4 a, float4 b) {
    return a.x * b.x + a.y * b.y + a.z * b.z + a.w * b.w;
}
__device__ __forceinline__ float4 ld4(const float* p) { return *(const float4*)p; }

// ---------------------------------------------------------------------------
// Kernel 0: build step matrices M, N0, N1 (one Dopri5 step == x' = M x + N0 u0 + N1 u1),
// ML = M^64, and convolution kernels F_j (v[b][c] = sum_j F_j u_{t0+j}).
// F build is LOG-DEPTH now: F_j = M^(63-j) H with H = N0' + M N1'; M^8 captured
// during the ML squarings; 7 serial seed steps + 7 parallel 8-chain steps
// (vs 64 serial iterations each paying a global-store vmcnt drain before).
// ---------------------------------------------------------------------------
__global__ __launch_bounds__(256) void k_pre(const float* __restrict__ tarr,
                                             const float* __restrict__ A,
                                             const float* __restrict__ B,
                                             float* __restrict__ ws) {
    __shared__ float sA[NS * NS], sB[NS * NI];
    __shared__ float Ka[6][NS * NS];
    __shared__ float Kb[6][NS * NI];
    __shared__ float Kc[6][NS * NI];
    __shared__ float Sa[NS * NS], Sb[NS * NI], Sc[NS * NI];
    __shared__ float Pq[2][NS * NS];
    __shared__ float Ms[NS * NS];

    const int tid = threadIdx.x;
    const float dt = tarr[1] - tarr[0];

    for (int e = tid; e < NS * NS; e += 256) sA[e] = A[e];
    for (int e = tid; e < NS * NI; e += 256) sB[e] = B[e];
    __syncthreads();
    for (int e = tid; e < NS * NS; e += 256) Ka[0][e] = sA[e];
    for (int e = tid; e < NS * NI; e += 256) { Kb[0][e] = sB[e]; Kc[0][e] = 0.f; }
    __syncthreads();

    const float atab[5][5] = {
        {0.2f, 0.f, 0.f, 0.f, 0.f},
        {3.f / 40.f, 9.f / 40.f, 0.f, 0.f, 0.f},
        {44.f / 45.f, -56.f / 15.f, 32.f / 9.f, 0.f, 0.f},
        {19372.f / 6561.f, -25360.f / 2187.f, 64448.f / 6561.f, -212.f / 729.f, 0.f},
        {9017.f / 3168.f, -355.f / 33.f, 46732.f / 5247.f, 49.f / 176.f, -5103.f / 18656.f}};
    const float ctab[6] = {0.f, 0.2f, 0.3f, 0.8f, 8.f / 9.f, 1.f};

    for (int st = 1; st <= 5; ++st) {
        for (int e = tid; e < NS * NS; e += 256) {
            float acc = 0.f;
            for (int j = 0; j < st; ++j) acc += atab[st - 1][j] * Ka[j][e];
            Sa[e] = acc;
        }
        for (int e = tid; e < NS * NI; e += 256) {
            float ab = 0.f, ac = 0.f;
            for (int j = 0; j < st; ++j) {
                ab += atab[st - 1][j] * Kb[j][e];
                ac += atab[st - 1][j] * Kc[j][e];
            }
            Sb[e] = ab; Sc[e] = ac;
        }
        __syncthreads();
        {
            const int j = tid & 31, ig = tid >> 5;
            for (int r = 0; r < 4; ++r) {
                const int row = ig + 8 * r;
                float acc = 0.f;
                for (int k = 0; k < NS; ++k) acc += sA[row * NS + k] * Sa[k * NS + j];
                Ka[st][row * NS + j] = sA[row * NS + j] + dt * acc;
            }
            const int jb = tid & 7, rb = tid >> 3;
            float ab = 0.f, ac = 0.f;
            for (int k = 0; k < NS; ++k) {
                ab += sA[rb * NS + k] * Sb[k * NI + jb];
                ac += sA[rb * NS + k] * Sc[k * NI + jb];
            }
            Kb[st][rb * NI + jb] = sB[rb * NI + jb] + dt * ab;
            Kc[st][rb * NI + jb] = ctab[st] * sB[rb * NI + jb] + dt * ac;
        }
        __syncthreads();
    }

    const float btab[6] = {35.f / 384.f, 0.f, 500.f / 1113.f, 125.f / 192.f,
                           -2187.f / 6784.f, 11.f / 84.f};
    for (int e = tid; e < NS * NS; e += 256) {
        float acc = 0.f;
        for (int i2 = 0; i2 < 6; ++i2) acc += btab[i2] * Ka[i2][e];
        const float m = dt * acc + (((e / NS) == (e % NS)) ? 1.f : 0.f);
        ws[WS_M + e] = m;
        Pq[0][e] = m;
        Ms[e] = m;  // live copy of M for the F build
    }
    for (int e = tid; e < NS * NI; e += 256) {
        float ap = 0.f, aq = 0.f;
        for (int i2 = 0; i2 < 6; ++i2) {
            ap += btab[i2] * Kb[i2][e];
            aq += btab[i2] * Kc[i2][e];
        }
        const float P = dt * ap, Q = dt * aq;
        ws[WS_N0 + e] = P - Q;  // coefficient of u_n
        ws[WS_N1 + e] = Q;      // coefficient of u_{n+1}
        Sb[e] = P - Q;          // N0'
        Sc[e] = Q;              // N1'
    }
    __syncthreads();

    // ML = M^64 via 6 squarings; capture M^8 into Sa (dead after RK stages).
    int cur = 0;
    for (int itq = 0; itq < 6; ++itq) {
        const int j = tid & 31, ig = tid >> 5;
        for (int r = 0; r < 4; ++r) {
            const int row = ig + 8 * r;
            float acc = 0.f;
            for (int k = 0; k < NS; ++k) acc += Pq[cur][row * NS + k] * Pq[cur][k * NS + j];
            Pq[cur ^ 1][row * NS + j] = acc;
        }
        __syncthreads();
        cur ^= 1;
        if (itq == 2)
            for (int e = tid; e < NS * NS; e += 256) Sa[e] = Pq[cur][e];  // M^8
    }
    for (int e = tid; e < NS * NS; e += 256) ws[WS_ML + e] = Pq[cur][e];

    // ---- F build, log depth. chainbuf pages alias Ka (dead). ----
    float* cb = &Ka[0][0];  // 2 pages x 8 chains x 256 el = 4096 floats <= 6144
    const int rr = tid >> 3, mm = tid & 7;

    float mrow[NS], m8row[NS];
#pragma unroll
    for (int kk = 0; kk < NS; ++kk) { mrow[kk] = Ms[rr * NS + kk]; m8row[kk] = Sa[rr * NS + kk]; }

    // H = N0' + M N1'  -> F_63 (seed 0)
    {
        float acc = 0.f;
#pragma unroll
        for (int kk = 0; kk < NS; ++kk) acc += mrow[kk] * Sc[kk * NI + mm];
        const float h = Sb[tid] + acc;
        cb[tid] = h;
        ws[WS_F + 63 * (NS * NI) + tid] = h;
    }
    __syncthreads();
    // seeds S_i = M^8 S_{i-1} -> F_{63-8i}
    for (int i = 1; i < 8; ++i) {
        float acc = 0.f;
#pragma unroll
        for (int kk = 0; kk < NS; ++kk) acc += m8row[kk] * cb[(i - 1) * 256 + kk * NI + mm];
        cb[i * 256 + tid] = acc;
        ws[WS_F + (63 - 8 * i) * (NS * NI) + tid] = acc;
        __syncthreads();
    }
    // 7 parallel steps: advance all 8 chains by M
    int pp = 0;
    for (int k = 1; k < 8; ++k) {
        float acc[8];
#pragma unroll
        for (int i = 0; i < 8; ++i) {
            float a = 0.f;
#pragma unroll
            for (int kk = 0; kk < NS; ++kk) a += mrow[kk] * cb[pp * 2048 + i * 256 + kk * NI + mm];
            acc[i] = a;
        }
#pragma unroll
        for (int i = 0; i < 8; ++i) {
            cb[(pp ^ 1) * 2048 + i * 256 + tid] = acc[i];
            ws[WS_F + (63 - 8 * i - k) * (NS * NI) + tid] = acc[i];
        }
        __syncthreads();
        pp ^= 1;
    }
    ws[WS_F + 64 * (NS * NI) + tid] = Sc[tid];  // F_64 = N1'
}

// ---------------------------------------------------------------------------
// Phase 1 (GEMM form, v3b): v[b][c] = sum_{j=0..64} F_j u_{t0+j}
// F[0..63] staged in 64 KB LDS transposed to sF[j][q][s8] (reads conflict-free:
// lane s8 -> bank group s8). Staging writes are now LINEAR in LDS (conflict-
// free; v3 had all 32 lanes on bank 0) with the permutation moved to the
// L2-resident global read side.
// ---------------------------------------------------------------------------
__global__ __launch_bounds__(256, 2) void k_phase1(const float* __restrict__ u,
                                                   float* __restrict__ ws) {
    __shared__ float4 sF[64 * 64];  // [j][q][s8], 65536 B

    const int tid = threadIdx.x;

    // linear LDS write; permuted global read: sF[j*64 + q*8 + s] = Fg[j*64 + s*8 + q]
    const float4* Fg = (const float4*)(ws + WS_F);
    for (int idx = tid; idx < 64 * 64; idx += 256) {
        const int j = idx >> 6, q = (idx >> 3) & 7, s = idx & 7;
        sF[idx] = Fg[(j << 6) + (s << 3) + q];
    }
    __syncthreads();

    const int task = blockIdx.x * 4 + (tid >> 6);
    const int c = task % (NCHUNKS - 1), g = task / (NCHUNKS - 1);
    const int l = tid & 63;
    const int beta = l >> 3, s8 = l & 7;
    const int b = g * 8 + beta;
    const int t0 = c * LCH;
    const float* ub = u + ((size_t)b * TT + t0) * NI;

    float4 ua = ld4(ub), uc = ld4(ub + 4);
    float a0 = 0.f, a1 = 0.f, a2 = 0.f, a3 = 0.f;

#pragma unroll 4
    for (int j = 0; j < 64; ++j) {
        // prefetch next u (always valid: t0+64 <= 4032)
        const float4 na = ld4(ub + (j + 1) * NI);
        const float4 nb = ld4(ub + (j + 1) * NI + 4);
        const float4* fj = &sF[(j << 6) + s8];
        const float4 f0 = fj[0], f1 = fj[8], f2 = fj[16], f3 = fj[24];
        const float4 f4 = fj[32], f5 = fj[40], f6 = fj[48], f7 = fj[56];
        a0 += dot4(f0, ua) + dot4(f1, uc);
        a1 += dot4(f2, ua) + dot4(f3, uc);
        a2 += dot4(f4, ua) + dot4(f5, uc);
        a3 += dot4(f6, ua) + dot4(f7, uc);
        ua = na; uc = nb;
    }

    // j = 64 tail: F_64 rows from global (tiny, L2-resident)
    const float* Ft = ws + WS_F + 64 * (NS * NI) + 32 * s8;
    a0 += dot4(ld4(Ft), ua) + dot4(ld4(Ft + 4), uc);
    a1 += dot4(ld4(Ft + 8), ua) + dot4(ld4(Ft + 12), uc);
    a2 += dot4(ld4(Ft + 16), ua) + dot4(ld4(Ft + 20), uc);
    a3 += dot4(ld4(Ft + 24), ua) + dot4(ld4(Ft + 28), uc);

    *(float4*)(ws + WS_V + ((size_t)b * NCHUNKS + c) * NS + 4 * s8) =
        make_float4(a0, a1, a2, a3);
}

// ---------------------------------------------------------------------------
// Phase 2: propagate chunk start states. One wave per batch.
// ---------------------------------------------------------------------------
__global__ __launch_bounds__(64) void k_phase2(const float* __restrict__ x0,
                                               float* __restrict__ ws) {
    const float* ML = ws + WS_ML;
    const float* v = ws + WS_V;
    float* sst = ws + WS_S;
    const int b = blockIdx.x;
    const int l = threadIdx.x, i = l & 31, h = l >> 5;

    float mlr[16];
#pragma unroll
    for (int jj = 0; jj < 16; ++jj) mlr[jj] = ML[i * NS + 16 * h + jj];

    float x = x0[b * NS + i];
    for (int c = 0; c < NCHUNKS; ++c) {
        if (h == 0) sst[((size_t)b * NCHUNKS + c) * NS + i] = x;
        if (c == NCHUNKS - 1) break;
        float p = 0.f;
#pragma unroll
        for (int jj = 0; jj < 16; ++jj) p += mlr[jj] * __shfl(x, 16 * h + jj, 64);
        p += __shfl_xor(p, 32, 64);
        x = p + v[((size_t)b * NCHUNKS + c) * NS + i];
    }
}

// ---------------------------------------------------------------------------
// Phase 3: replay chunks, writing xs and ys (fused). Wave-synchronous (no
// __syncthreads -> no vmcnt drain on the serial chain). u prefetch is 1-ahead:
// the ~400-cyc M*x FMA block covers the load latency, and dropping 2-ahead
// frees 8 VGPRs so __launch_bounds__(64,3) fits 3 waves/SIMD (was 2 at 172
// VGPR -> VALUBusy 48%).
// ---------------------------------------------------------------------------
__global__ __launch_bounds__(64, 3) void k_phase3(const float* __restrict__ u,
                                                  float* __restrict__ ws,
                                                  float* __restrict__ out,
                                                  const float* __restrict__ Cc,
                                                  const float* __restrict__ Dd) {
    const float* M = ws + WS_M;
    const float* N0 = ws + WS_N0;
    const float* N1 = ws + WS_N1;

    const int task = blockIdx.x;
    const int c = task % NCHUNKS, g = task / NCHUNKS;
    const int l = threadIdx.x;
    const int beta = l >> 3, s8 = l & 7;
    const int b = g * 8 + beta;

    // cache M rows 4*s8 .. 4*s8+3 (128 VGPRs)
    float4 mq[4][8];
#pragma unroll
    for (int r = 0; r < 4; ++r)
#pragma unroll
        for (int jj = 0; jj < 8; ++jj) mq[r][jj] = ld4(M + (4 * s8 + r) * NS + 4 * jj);

    float4 n0q[4][2], n1q[4][2];
#pragma unroll
    for (int r = 0; r < 4; ++r) {
        n0q[r][0] = ld4(N0 + (4 * s8 + r) * NI);
        n0q[r][1] = ld4(N0 + (4 * s8 + r) * NI + 4);
        n1q[r][0] = ld4(N1 + (4 * s8 + r) * NI);
        n1q[r][1] = ld4(N1 + (4 * s8 + r) * NI + 4);
    }

    float4 cq[8], dq[2];
#pragma unroll
    for (int jj = 0; jj < 8; ++jj) cq[jj] = ld4(Cc + s8 * NS + 4 * jj);
    dq[0] = ld4(Dd + s8 * NI);
    dq[1] = ld4(Dd + s8 * NI + 4);

    // per-wave x buffer, double-buffered; row stride 9 float4 (conflict-free).
    __shared__ float4 xb[2][8 * 9];

    const int t0 = c * LCH;
    const float* ub = u + (size_t)b * TT * NI;
    float4 u0a = ld4(ub + t0 * NI), u0b = ld4(ub + t0 * NI + 4);

    float4 mine = ld4(ws + WS_S + ((size_t)b * NCHUNKS + c) * NS + 4 * s8);
    xb[0][beta * 9 + s8] = mine;
    asm volatile("s_waitcnt lgkmcnt(0)" ::: "memory");
    __builtin_amdgcn_sched_barrier(0);

    float* yout = out + (size_t)BATCH * TT * NS;
    int cur = 0;
    for (int js = 0; js < LCH; ++js) {
        const int t = t0 + js;
        float4 xq[8];
#pragma unroll
        for (int jj = 0; jj < 8; ++jj) xq[jj] = xb[cur][beta * 9 + jj];

        // store xs[b][t][4*s8 .. 4*s8+3] (value held from prev step / init)
        *(float4*)(out + ((size_t)b * TT + t) * NS + 4 * s8) = mine;
        // y[b][t][o], o == s8
        float yv = 0.f;
#pragma unroll
        for (int jj = 0; jj < 8; ++jj) yv += dot4(cq[jj], xq[jj]);
        yv += dot4(dq[0], u0a) + dot4(dq[1], u0b);
        yout[((size_t)b * TT + t) * NO + s8] = yv;

        if (js < LCH - 1) {
            // issue u[t+1] early; consumed only after the M*x FMA block
            const float4 u1a = ld4(ub + (t + 1) * NI);
            const float4 u1b = ld4(ub + (t + 1) * NI + 4);
            float w0 = dot4(n0q[0][0], u0a) + dot4(n0q[0][1], u0b);
            float w1 = dot4(n0q[1][0], u0a) + dot4(n0q[1][1], u0b);
            float w2 = dot4(n0q[2][0], u0a) + dot4(n0q[2][1], u0b);
            float w3 = dot4(n0q[3][0], u0a) + dot4(n0q[3][1], u0b);
#pragma unroll
            for (int jj = 0; jj < 8; ++jj) {
                const float4 xv = xq[jj];
                w0 += dot4(mq[0][jj], xv);
                w1 += dot4(mq[1][jj], xv);
                w2 += dot4(mq[2][jj], xv);
                w3 += dot4(mq[3][jj], xv);
            }
            w0 += dot4(n1q[0][0], u1a) + dot4(n1q[0][1], u1b);
            w1 += dot4(n1q[1][0], u1a) + dot4(n1q[1][1], u1b);
            w2 += dot4(n1q[2][0], u1a) + dot4(n1q[2][1], u1b);
            w3 += dot4(n1q[3][0], u1a) + dot4(n1q[3][1], u1b);
            mine = make_float4(w0, w1, w2, w3);
            xb[cur ^ 1][beta * 9 + s8] = mine;
            u0a = u1a; u0b = u1b;
        }
        asm volatile("s_waitcnt lgkmcnt(0)" ::: "memory");
        __builtin_amdgcn_sched_barrier(0);
        cur ^= 1;
    }
}

extern "C" void kernel_launch(void* const* d_in, const int* in_sizes, int n_in,
                              void* d_out, int out_size, void* d_ws, size_t ws_size,
                              hipStream_t stream) {
    const float* t = (const float*)d_in[0];
    const float* u = (const float*)d_in[1];
    const float* x0 = (const float*)d_in[2];
    const float* A = (const float*)d_in[3];
    const float* B = (const float*)d_in[4];
    const float* C = (const float*)d_in[5];
    const float* D = (const float*)d_in[6];
    float* out = (float*)d_out;
    float* ws = (float*)d_ws;

    k_pre<<<dim3(1), dim3(256), 0, stream>>>(t, A, B, ws);
    k_phase1<<<dim3(8 * (NCHUNKS - 1)), dim3(256), 0, stream>>>(u, ws);
    k_phase2<<<dim3(BATCH), dim3(64), 0, stream>>>(x0, ws);
    k_phase3<<<dim3(32 * NCHUNKS), dim3(64), 0, stream>>>(u, ws, out, C, D);
}

// Round 6
// 342.010 us; speedup vs baseline: 3.8974x; 3.8974x over previous
//
#include <hip/hip_runtime.h>

#define BATCH 256
#define TT 4096
#define NS 32
#define NI 8
#define NO 8
#define LCH 64
#define NCHUNKS 64  // TT / LCH

// ws layout (floats)
#define WS_M  0
#define WS_N0 1024
#define WS_N1 1280
#define WS_ML 1536
#define WS_V  2560
#define WS_S  (2560 + BATCH * NCHUNKS * NS)
#define WS_F  (WS_S + BATCH * NCHUNKS * NS)  // [LCH+1][NS][NI]

__device__ __forceinline__ float dot4(float4 a, float4 b) {
    return a.x * b.x + a.y * b.y + a.z * b.z + a.w * b.w;
}
__device__ __forceinline__ float4 ld4(const float* p) { return *(const float4*)p; }

// ---------------------------------------------------------------------------
// Kernel 0: build step matrices M, N0, N1 (one Dopri5 step == x' = M x + N0 u0 + N1 u1),
// ML = M^64, and convolution kernels F_j (v[b][c] = sum_j F_j u_{t0+j}).
// F build is log-depth: F_j = M^(63-j) H with H = N0' + M N1'; M^8 captured
// during the ML squarings; 7 serial seed steps + 7 parallel 8-chain steps.
// ---------------------------------------------------------------------------
__global__ __launch_bounds__(256) void k_pre(const float* __restrict__ tarr,
                                             const float* __restrict__ A,
                                             const float* __restrict__ B,
                                             float* __restrict__ ws) {
    __shared__ float sA[NS * NS], sB[NS * NI];
    __shared__ float Ka[6][NS * NS];
    __shared__ float Kb[6][NS * NI];
    __shared__ float Kc[6][NS * NI];
    __shared__ float Sa[NS * NS], Sb[NS * NI], Sc[NS * NI];
    __shared__ float Pq[2][NS * NS];
    __shared__ float Ms[NS * NS];

    const int tid = threadIdx.x;
    const float dt = tarr[1] - tarr[0];

    for (int e = tid; e < NS * NS; e += 256) sA[e] = A[e];
    for (int e = tid; e < NS * NI; e += 256) sB[e] = B[e];
    __syncthreads();
    for (int e = tid; e < NS * NS; e += 256) Ka[0][e] = sA[e];
    for (int e = tid; e < NS * NI; e += 256) { Kb[0][e] = sB[e]; Kc[0][e] = 0.f; }
    __syncthreads();

    const float atab[5][5] = {
        {0.2f, 0.f, 0.f, 0.f, 0.f},
        {3.f / 40.f, 9.f / 40.f, 0.f, 0.f, 0.f},
        {44.f / 45.f, -56.f / 15.f, 32.f / 9.f, 0.f, 0.f},
        {19372.f / 6561.f, -25360.f / 2187.f, 64448.f / 6561.f, -212.f / 729.f, 0.f},
        {9017.f / 3168.f, -355.f / 33.f, 46732.f / 5247.f, 49.f / 176.f, -5103.f / 18656.f}};
    const float ctab[6] = {0.f, 0.2f, 0.3f, 0.8f, 8.f / 9.f, 1.f};

    for (int st = 1; st <= 5; ++st) {
        for (int e = tid; e < NS * NS; e += 256) {
            float acc = 0.f;
            for (int j = 0; j < st; ++j) acc += atab[st - 1][j] * Ka[j][e];
            Sa[e] = acc;
        }
        for (int e = tid; e < NS * NI; e += 256) {
            float ab = 0.f, ac = 0.f;
            for (int j = 0; j < st; ++j) {
                ab += atab[st - 1][j] * Kb[j][e];
                ac += atab[st - 1][j] * Kc[j][e];
            }
            Sb[e] = ab; Sc[e] = ac;
        }
        __syncthreads();
        {
            const int j = tid & 31, ig = tid >> 5;
            for (int r = 0; r < 4; ++r) {
                const int row = ig + 8 * r;
                float acc = 0.f;
                for (int k = 0; k < NS; ++k) acc += sA[row * NS + k] * Sa[k * NS + j];
                Ka[st][row * NS + j] = sA[row * NS + j] + dt * acc;
            }
            const int jb = tid & 7, rb = tid >> 3;
            float ab = 0.f, ac = 0.f;
            for (int k = 0; k < NS; ++k) {
                ab += sA[rb * NS + k] * Sb[k * NI + jb];
                ac += sA[rb * NS + k] * Sc[k * NI + jb];
            }
            Kb[st][rb * NI + jb] = sB[rb * NI + jb] + dt * ab;
            Kc[st][rb * NI + jb] = ctab[st] * sB[rb * NI + jb] + dt * ac;
        }
        __syncthreads();
    }

    const float btab[6] = {35.f / 384.f, 0.f, 500.f / 1113.f, 125.f / 192.f,
                           -2187.f / 6784.f, 11.f / 84.f};
    for (int e = tid; e < NS * NS; e += 256) {
        float acc = 0.f;
        for (int i2 = 0; i2 < 6; ++i2) acc += btab[i2] * Ka[i2][e];
        const float m = dt * acc + (((e / NS) == (e % NS)) ? 1.f : 0.f);
        ws[WS_M + e] = m;
        Pq[0][e] = m;
        Ms[e] = m;  // live copy of M for the F build
    }
    for (int e = tid; e < NS * NI; e += 256) {
        float ap = 0.f, aq = 0.f;
        for (int i2 = 0; i2 < 6; ++i2) {
            ap += btab[i2] * Kb[i2][e];
            aq += btab[i2] * Kc[i2][e];
        }
        const float P = dt * ap, Q = dt * aq;
        ws[WS_N0 + e] = P - Q;  // coefficient of u_n
        ws[WS_N1 + e] = Q;      // coefficient of u_{n+1}
        Sb[e] = P - Q;          // N0'
        Sc[e] = Q;              // N1'
    }
    __syncthreads();

    // ML = M^64 via 6 squarings; capture M^8 into Sa (dead after RK stages).
    int cur = 0;
    for (int itq = 0; itq < 6; ++itq) {
        const int j = tid & 31, ig = tid >> 5;
        for (int r = 0; r < 4; ++r) {
            const int row = ig + 8 * r;
            float acc = 0.f;
            for (int k = 0; k < NS; ++k) acc += Pq[cur][row * NS + k] * Pq[cur][k * NS + j];
            Pq[cur ^ 1][row * NS + j] = acc;
        }
        __syncthreads();
        cur ^= 1;
        if (itq == 2)
            for (int e = tid; e < NS * NS; e += 256) Sa[e] = Pq[cur][e];  // M^8
    }
    for (int e = tid; e < NS * NS; e += 256) ws[WS_ML + e] = Pq[cur][e];

    // ---- F build, log depth. chainbuf pages alias Ka (dead). ----
    float* cb = &Ka[0][0];  // 2 pages x 8 chains x 256 el = 4096 floats <= 6144
    const int rr = tid >> 3, mm = tid & 7;

    float mrow[NS], m8row[NS];
#pragma unroll
    for (int kk = 0; kk < NS; ++kk) { mrow[kk] = Ms[rr * NS + kk]; m8row[kk] = Sa[rr * NS + kk]; }

    // H = N0' + M N1'  -> F_63 (seed 0)
    {
        float acc = 0.f;
#pragma unroll
        for (int kk = 0; kk < NS; ++kk) acc += mrow[kk] * Sc[kk * NI + mm];
        const float h = Sb[tid] + acc;
        cb[tid] = h;
        ws[WS_F + 63 * (NS * NI) + tid] = h;
    }
    __syncthreads();
    // seeds S_i = M^8 S_{i-1} -> F_{63-8i}
    for (int i = 1; i < 8; ++i) {
        float acc = 0.f;
#pragma unroll
        for (int kk = 0; kk < NS; ++kk) acc += m8row[kk] * cb[(i - 1) * 256 + kk * NI + mm];
        cb[i * 256 + tid] = acc;
        ws[WS_F + (63 - 8 * i) * (NS * NI) + tid] = acc;
        __syncthreads();
    }
    // 7 parallel steps: advance all 8 chains by M
    int pp = 0;
    for (int k = 1; k < 8; ++k) {
        float acc[8];
#pragma unroll
        for (int i = 0; i < 8; ++i) {
            float a = 0.f;
#pragma unroll
            for (int kk = 0; kk < NS; ++kk) a += mrow[kk] * cb[pp * 2048 + i * 256 + kk * NI + mm];
            acc[i] = a;
        }
#pragma unroll
        for (int i = 0; i < 8; ++i) {
            cb[(pp ^ 1) * 2048 + i * 256 + tid] = acc[i];
            ws[WS_F + (63 - 8 * i - k) * (NS * NI) + tid] = acc[i];
        }
        __syncthreads();
        pp ^= 1;
    }
    ws[WS_F + 64 * (NS * NI) + tid] = Sc[tid];  // F_64 = N1'
}

// ---------------------------------------------------------------------------
// Phase 1 (GEMM form, v3b): v[b][c] = sum_{j=0..64} F_j u_{t0+j}
// F[0..63] staged in 64 KB LDS transposed to sF[j][q][s8] (reads conflict-free);
// staging writes linear in LDS, permutation on the L2-resident global read.
// ---------------------------------------------------------------------------
__global__ __launch_bounds__(256, 2) void k_phase1(const float* __restrict__ u,
                                                   float* __restrict__ ws) {
    __shared__ float4 sF[64 * 64];  // [j][q][s8], 65536 B

    const int tid = threadIdx.x;

    // linear LDS write; permuted global read: sF[j*64 + q*8 + s] = Fg[j*64 + s*8 + q]
    const float4* Fg = (const float4*)(ws + WS_F);
    for (int idx = tid; idx < 64 * 64; idx += 256) {
        const int j = idx >> 6, q = (idx >> 3) & 7, s = idx & 7;
        sF[idx] = Fg[(j << 6) + (s << 3) + q];
    }
    __syncthreads();

    const int task = blockIdx.x * 4 + (tid >> 6);
    const int c = task % (NCHUNKS - 1), g = task / (NCHUNKS - 1);
    const int l = tid & 63;
    const int beta = l >> 3, s8 = l & 7;
    const int b = g * 8 + beta;
    const int t0 = c * LCH;
    const float* ub = u + ((size_t)b * TT + t0) * NI;

    float4 ua = ld4(ub), uc = ld4(ub + 4);
    float a0 = 0.f, a1 = 0.f, a2 = 0.f, a3 = 0.f;

#pragma unroll 4
    for (int j = 0; j < 64; ++j) {
        // prefetch next u (always valid: t0+64 <= 4032)
        const float4 na = ld4(ub + (j + 1) * NI);
        const float4 nb = ld4(ub + (j + 1) * NI + 4);
        const float4* fj = &sF[(j << 6) + s8];
        const float4 f0 = fj[0], f1 = fj[8], f2 = fj[16], f3 = fj[24];
        const float4 f4 = fj[32], f5 = fj[40], f6 = fj[48], f7 = fj[56];
        a0 += dot4(f0, ua) + dot4(f1, uc);
        a1 += dot4(f2, ua) + dot4(f3, uc);
        a2 += dot4(f4, ua) + dot4(f5, uc);
        a3 += dot4(f6, ua) + dot4(f7, uc);
        ua = na; uc = nb;
    }

    // j = 64 tail: F_64 rows from global (tiny, L2-resident)
    const float* Ft = ws + WS_F + 64 * (NS * NI) + 32 * s8;
    a0 += dot4(ld4(Ft), ua) + dot4(ld4(Ft + 4), uc);
    a1 += dot4(ld4(Ft + 8), ua) + dot4(ld4(Ft + 12), uc);
    a2 += dot4(ld4(Ft + 16), ua) + dot4(ld4(Ft + 20), uc);
    a3 += dot4(ld4(Ft + 24), ua) + dot4(ld4(Ft + 28), uc);

    *(float4*)(ws + WS_V + ((size_t)b * NCHUNKS + c) * NS + 4 * s8) =
        make_float4(a0, a1, a2, a3);
}

// ---------------------------------------------------------------------------
// Phase 2: propagate chunk start states. One wave per batch.
// ---------------------------------------------------------------------------
__global__ __launch_bounds__(64) void k_phase2(const float* __restrict__ x0,
                                               float* __restrict__ ws) {
    const float* ML = ws + WS_ML;
    const float* v = ws + WS_V;
    float* sst = ws + WS_S;
    const int b = blockIdx.x;
    const int l = threadIdx.x, i = l & 31, h = l >> 5;

    float mlr[16];
#pragma unroll
    for (int jj = 0; jj < 16; ++jj) mlr[jj] = ML[i * NS + 16 * h + jj];

    float x = x0[b * NS + i];
    for (int c = 0; c < NCHUNKS; ++c) {
        if (h == 0) sst[((size_t)b * NCHUNKS + c) * NS + i] = x;
        if (c == NCHUNKS - 1) break;
        float p = 0.f;
#pragma unroll
        for (int jj = 0; jj < 16; ++jj) p += mlr[jj] * __shfl(x, 16 * h + jj, 64);
        p += __shfl_xor(p, 32, 64);
        x = p + v[((size_t)b * NCHUNKS + c) * NS + i];
    }
}

// ---------------------------------------------------------------------------
// Phase 3: replay chunks from true start states, writing xs and ys (fused).
// EXACT round-4 configuration (111 us, VGPR 172): wave-synchronous, no
// __syncthreads (no vmcnt drain on the serial chain), u prefetched 2 ahead,
// __launch_bounds__(64,1). DO NOT cap VGPRs below demand: (64,3) forced 84
// VGPR -> spill -> 2.9 GB scratch fetch, 1099 us (round 5).
// ---------------------------------------------------------------------------
__global__ __launch_bounds__(64, 1) void k_phase3(const float* __restrict__ u,
                                                  float* __restrict__ ws,
                                                  float* __restrict__ out,
                                                  const float* __restrict__ Cc,
                                                  const float* __restrict__ Dd) {
    const float* M = ws + WS_M;
    const float* N0 = ws + WS_N0;
    const float* N1 = ws + WS_N1;

    const int task = blockIdx.x;
    const int c = task % NCHUNKS, g = task / NCHUNKS;
    const int l = threadIdx.x;
    const int beta = l >> 3, s8 = l & 7;
    const int b = g * 8 + beta;

    // cache M rows 4*s8 .. 4*s8+3 (128 VGPRs)
    float4 mq[4][8];
#pragma unroll
    for (int r = 0; r < 4; ++r)
#pragma unroll
        for (int jj = 0; jj < 8; ++jj) mq[r][jj] = ld4(M + (4 * s8 + r) * NS + 4 * jj);

    float4 n0q[4][2], n1q[4][2];
#pragma unroll
    for (int r = 0; r < 4; ++r) {
        n0q[r][0] = ld4(N0 + (4 * s8 + r) * NI);
        n0q[r][1] = ld4(N0 + (4 * s8 + r) * NI + 4);
        n1q[r][0] = ld4(N1 + (4 * s8 + r) * NI);
        n1q[r][1] = ld4(N1 + (4 * s8 + r) * NI + 4);
    }

    float4 cq[8], dq[2];
#pragma unroll
    for (int jj = 0; jj < 8; ++jj) cq[jj] = ld4(Cc + s8 * NS + 4 * jj);
    dq[0] = ld4(Dd + s8 * NI);
    dq[1] = ld4(Dd + s8 * NI + 4);

    // per-wave x buffer, double-buffered; row stride 9 float4 (conflict-free).
    __shared__ float4 xb[2][8 * 9];

    const int t0 = c * LCH;
    const float* ub = u + (size_t)b * TT * NI;
    float4 u0a = ld4(ub + t0 * NI), u0b = ld4(ub + t0 * NI + 4);
    float4 u1a = ld4(ub + (t0 + 1) * NI), u1b = ld4(ub + (t0 + 1) * NI + 4);

    float4 mine = ld4(ws + WS_S + ((size_t)b * NCHUNKS + c) * NS + 4 * s8);
    xb[0][beta * 9 + s8] = mine;
    asm volatile("s_waitcnt lgkmcnt(0)" ::: "memory");
    __builtin_amdgcn_sched_barrier(0);

    float* yout = out + (size_t)BATCH * TT * NS;
    int cur = 0;
    for (int js = 0; js < LCH; ++js) {
        const int t = t0 + js;
        float4 xq[8];
#pragma unroll
        for (int jj = 0; jj < 8; ++jj) xq[jj] = xb[cur][beta * 9 + jj];

        // prefetch u[t+2] (becomes u1 next iteration); clamp keeps it in-bounds,
        // redundant values on the last two steps are never consumed.
        const int tp = (t + 2 < TT - 1) ? (t + 2) : (TT - 1);
        const float4 u2a = ld4(ub + tp * NI);
        const float4 u2b = ld4(ub + tp * NI + 4);

        // store xs[b][t][4*s8 .. 4*s8+3] (value held from prev step / init)
        *(float4*)(out + ((size_t)b * TT + t) * NS + 4 * s8) = mine;
        // y[b][t][o], o == s8
        float yv = 0.f;
#pragma unroll
        for (int jj = 0; jj < 8; ++jj) yv += dot4(cq[jj], xq[jj]);
        yv += dot4(dq[0], u0a) + dot4(dq[1], u0b);
        yout[((size_t)b * TT + t) * NO + s8] = yv;

        if (js < LCH - 1) {
            float w0 = dot4(n0q[0][0], u0a) + dot4(n0q[0][1], u0b) + dot4(n1q[0][0], u1a) + dot4(n1q[0][1], u1b);
            float w1 = dot4(n0q[1][0], u0a) + dot4(n0q[1][1], u0b) + dot4(n1q[1][0], u1a) + dot4(n1q[1][1], u1b);
            float w2 = dot4(n0q[2][0], u0a) + dot4(n0q[2][1], u0b) + dot4(n1q[2][0], u1a) + dot4(n1q[2][1], u1b);
            float w3 = dot4(n0q[3][0], u0a) + dot4(n0q[3][1], u0b) + dot4(n1q[3][0], u1a) + dot4(n1q[3][1], u1b);
#pragma unroll
            for (int jj = 0; jj < 8; ++jj) {
                const float4 xv = xq[jj];
                w0 += dot4(mq[0][jj], xv);
                w1 += dot4(mq[1][jj], xv);
                w2 += dot4(mq[2][jj], xv);
                w3 += dot4(mq[3][jj], xv);
            }
            mine = make_float4(w0, w1, w2, w3);
            xb[cur ^ 1][beta * 9 + s8] = mine;
            u0a = u1a; u0b = u1b;
            u1a = u2a; u1b = u2b;
        }
        asm volatile("s_waitcnt lgkmcnt(0)" ::: "memory");
        __builtin_amdgcn_sched_barrier(0);
        cur ^= 1;
    }
}

extern "C" void kernel_launch(void* const* d_in, const int* in_sizes, int n_in,
                              void* d_out, int out_size, void* d_ws, size_t ws_size,
                              hipStream_t stream) {
    const float* t = (const float*)d_in[0];
    const float* u = (const float*)d_in[1];
    const float* x0 = (const float*)d_in[2];
    const float* A = (const float*)d_in[3];
    const float* B = (const float*)d_in[4];
    const float* C = (const float*)d_in[5];
    const float* D = (const float*)d_in[6];
    float* out = (float*)d_out;
    float* ws = (float*)d_ws;

    k_pre<<<dim3(1), dim3(256), 0, stream>>>(t, A, B, ws);
    k_phase1<<<dim3(8 * (NCHUNKS - 1)), dim3(256), 0, stream>>>(u, ws);
    k_phase2<<<dim3(BATCH), dim3(64), 0, stream>>>(x0, ws);
    k_phase3<<<dim3(32 * NCHUNKS), dim3(64), 0, stream>>>(u, ws, out, C, D);
}